// Round 5
// baseline (644.505 us; speedup 1.0000x reference)
//
#include <hip/hip_runtime.h>
#include <hip/hip_bf16.h>
#include <math.h>

#define N_NODES 50000
#define N_EDGES 800000
#define IN_F 256
#define G 128                    // 2*HID
#define NHID 64
#define NGRAPH 32
#define NBUCK ((N_NODES + 255) / 256)    // 196 buckets (dst>>8)
#define CAPB 8192                         // srcs capacity per bucket (mean 4352+256)
#define CELL 64                           // pairs capacity per (bucket, binA-block)
#define EPB 4096                          // edges per binA block
#define NBA ((N_EDGES + EPB - 1) / EPB)   // 196 (real edges only; self-loops direct)

typedef __hip_bfloat16 bf16;
typedef unsigned short ushort;
typedef __attribute__((ext_vector_type(8))) short short8;
typedef __attribute__((ext_vector_type(4))) float f32x4;
typedef __attribute__((ext_vector_type(4))) unsigned u32x4;
typedef __attribute__((ext_vector_type(4))) short s16x4;

// ---------- dtype-agnostic loads ----------
__device__ __forceinline__ float bf2f(ushort u) {
    union { unsigned u; float f; } c; c.u = ((unsigned)u) << 16; return c.f;
}
// round-to-nearest-even f32 -> bf16 (finite inputs)
__device__ __forceinline__ ushort f2bf(float f) {
    unsigned u = __float_as_uint(f);
    u += 0x7FFFu + ((u >> 16) & 1u);
    return (ushort)(u >> 16);
}
__device__ __forceinline__ float ldf(const void* p, long i, int f32) {
    return f32 ? ((const float*)p)[i] : bf2f(((const ushort*)p)[i]);
}
__device__ __forceinline__ int ldi(const void* p, long i, int i64) {
    return i64 ? (int)((const long long*)p)[i] : ((const int*)p)[i];
}

__device__ __forceinline__ float selu_f(float x) {
    const float sc = 1.0507009873554805f, al = 1.6732632423543772f;
    return x > 0.f ? sc * x : sc * al * expm1f(x);
}

// async global->LDS, 16 B/lane; lds base must be wave-uniform.
typedef const __attribute__((address_space(1))) void gas_void;
typedef __attribute__((address_space(3))) void las_void;
__device__ __forceinline__ void stage16(const void* g, void* l) {
    __builtin_amdgcn_global_load_lds((gas_void*)g, (las_void*)l, 16, 0, 0);
}

__device__ __forceinline__ void edge_sd(const void* __restrict__ ei, int e, int i64,
                                        int& s, int& d) {
    s = ldi(ei, e, i64);
    d = ldi(ei, (long)N_EDGES + e, i64);
    s = min(max(s, 0), N_NODES - 1);
    d = min(max(d, 0), N_NODES - 1);
}

// ---------------- CSR build v5: cells + direct self-loop insertion ---------------
// binA block k writes bucket-b records to cell (b,k), CELL=64 capacity. Only the
// 800K REAL edges stream through binA (Poisson(21)/cell -> P(>64)~1e-14); the
// 50K self-loops are inserted deterministically by binB at slot 0 of each node's
// range. cnts[b][k] fully overwritten -> no pre-zeroing. Inline dtype detect;
// fused wt.

__global__ __launch_bounds__(256) void binA_kernel(
    const void* __restrict__ ei, unsigned* __restrict__ pairs,
    int* __restrict__ cnts, int* __restrict__ flags,
    const void* __restrict__ x,
    const void* __restrict__ W1, const void* __restrict__ W2,
    ushort* __restrict__ wt1, ushort* __restrict__ wt2) {
    __shared__ int cnt[256], lofs[256], pcur[256];
    __shared__ unsigned stage[EPB];
    __shared__ int s_i64, s_f32;
    int t = threadIdx.x;

    // ---- inline dtype detect: wave0 -> i64 flag, wave1 -> f32 flag ----
    if (t < 64) {
        const unsigned* wu = (const unsigned*)ei;
        long j = 1 + (long)t * 24986;           // odd dwords, < 1.6M (int32-safe)
        unsigned long long bal = __ballot(wu[j] != 0u);
        if (t == 0) s_i64 = (__popcll(bal) < 16) ? 1 : 0;   // i64: high words all 0
    } else if (t < 128) {
        const unsigned* xu = (const unsigned*)x;
        unsigned u = xu[(long)(t - 64) * 100000];           // < 6.4M dwords (bf16-safe)
        unsigned e = (u >> 23) & 0xFF;
        unsigned long long bal = __ballot(u == 0u || (e >= 100 && e <= 140));
        if (t == 64) s_f32 = (__popcll(bal) >= 32) ? 1 : 0;
    }
    cnt[t] = 0;
    __syncthreads();
    int i64 = s_i64, f32 = s_f32;
    if (blockIdx.x == 0 && t == 0) { flags[0] = f32; flags[1] = i64; }

    int e0 = blockIdx.x * EPB;
    int nE = min(EPB, N_EDGES - e0);
    int sj[EPB / 256], dj[EPB / 256];
#pragma unroll
    for (int j = 0; j < EPB / 256; j++) {
        int idx = j * 256 + t;
        if (idx < nE) {
            edge_sd(ei, e0 + idx, i64, sj[j], dj[j]);
            atomicAdd(&cnt[dj[j] >> 8], 1);
        } else dj[j] = -1;
    }
    __syncthreads();
    lofs[t] = cnt[t];
    for (int off = 1; off < 256; off <<= 1) {
        __syncthreads();
        int v = (t >= off) ? lofs[t - off] : 0;
        __syncthreads();
        lofs[t] += v;
    }
    __syncthreads();
    int excl = lofs[t] - cnt[t];
    __syncthreads();
    lofs[t] = excl;
    pcur[t] = excl;
    __syncthreads();
#pragma unroll
    for (int j = 0; j < EPB / 256; j++) {
        if (dj[j] >= 0) {
            int b = dj[j] >> 8;
            int lp = atomicAdd(&pcur[b], 1);
            stage[lp] = (unsigned)sj[j] | ((unsigned)(dj[j] & 255) << 16) |
                        ((unsigned)b << 24);
        }
    }
    __syncthreads();
    for (int i = t; i < nE; i += 256) {      // per-bucket contiguous cell writes
        unsigned p = stage[i];
        int b = p >> 24;
        int off2 = i - lofs[b];
        if (off2 < CELL)
            pairs[((size_t)b * NBA + blockIdx.x) * CELL + off2] = p;
    }
    if (t < NBUCK) cnts[(size_t)t * NBA + blockIdx.x] = min(cnt[t], CELL);

    // ---- fused wt: split-bf16 (hi+lo) frag-reorder of W1,W2 (NBA*256 >= 49152) --
    int wi = blockIdx.x * 256 + t;
    if (wi < IN_F * G + G * G) {
        const void* W; ushort* wtp; int idx;
        if (wi < IN_F * G) { W = W1; wtp = wt1; idx = wi; }
        else { W = W2; wtp = wt2; idx = wi - IN_F * G; }
        int k = idx >> 7, n = idx & (G - 1);
        float wv = ldf(W, idx, f32);
        ushort h = f2bf(wv);
        ushort lo = f2bf(wv - bf2f(h));
        int c = k >> 5, q = (k >> 3) & 3, j = k & 7;
        int nt = n >> 4, n16 = n & 15;
        int lane = q * 16 + n16;
        size_t base = ((size_t)c * 16 + nt * 2) * 512 + lane * 8 + j;
        wtp[base] = h;           // hilo = 0
        wtp[base + 512] = lo;    // hilo = 1
    }
}

// binB: per-bucket node count/scan -> rowse, self-loop at slot 0, scatter cells.
__device__ __forceinline__ void binB_body(
    const unsigned* __restrict__ pairs, const int* __restrict__ cnts,
    int2* __restrict__ rowse, ushort* __restrict__ srcs,
    int b, int t, int* cnt, int* cur, int* ccnt) {
    if (t < NBA) ccnt[t] = cnts[(size_t)b * NBA + t];
    int node = b * 256 + t;
    int valid = (node < N_NODES) ? 1 : 0;
    cnt[t] = valid;                        // reserve the self-loop slot
    __syncthreads();
    if (t < NBA) {                         // thread t streams cell (b,t), 4-batched
        const unsigned* cp = pairs + ((size_t)b * NBA + t) * CELL;
        int n = ccnt[t], i = 0;
        for (; i + 4 <= n; i += 4) {
            unsigned r0 = cp[i], r1 = cp[i + 1], r2 = cp[i + 2], r3 = cp[i + 3];
            atomicAdd(&cnt[(r0 >> 16) & 255], 1);
            atomicAdd(&cnt[(r1 >> 16) & 255], 1);
            atomicAdd(&cnt[(r2 >> 16) & 255], 1);
            atomicAdd(&cnt[(r3 >> 16) & 255], 1);
        }
        for (; i < n; i++) atomicAdd(&cnt[(cp[i] >> 16) & 255], 1);
    }
    __syncthreads();
    cur[t] = cnt[t];
    for (int off = 1; off < 256; off <<= 1) {
        __syncthreads();
        int v = (t >= off) ? cur[t - off] : 0;
        __syncthreads();
        cur[t] += v;
    }
    int excl = cur[t] - cnt[t];
    int base = b * CAPB;
    int myCnt = cnt[t];
    __syncthreads();
    if (valid) {
        srcs[base + excl] = (ushort)node;  // self-loop at slot 0
        rowse[node] = make_int2(base + excl, base + excl + myCnt);
    }
    cur[t] = base + excl + valid;
    __syncthreads();
    if (t < NBA) {
        const unsigned* cp = pairs + ((size_t)b * NBA + t) * CELL;
        int n = ccnt[t], i = 0;
        for (; i + 4 <= n; i += 4) {
            unsigned r0 = cp[i], r1 = cp[i + 1], r2 = cp[i + 2], r3 = cp[i + 3];
            int p0 = atomicAdd(&cur[(r0 >> 16) & 255], 1);
            int p1 = atomicAdd(&cur[(r1 >> 16) & 255], 1);
            int p2 = atomicAdd(&cur[(r2 >> 16) & 255], 1);
            int p3 = atomicAdd(&cur[(r3 >> 16) & 255], 1);
            srcs[p0] = (ushort)(r0 & 0xFFFFu);
            srcs[p1] = (ushort)(r1 & 0xFFFFu);
            srcs[p2] = (ushort)(r2 & 0xFFFFu);
            srcs[p3] = (ushort)(r3 & 0xFFFFu);
        }
        for (; i < n; i++) {
            unsigned r = cp[i];
            int p = atomicAdd(&cur[(r >> 16) & 255], 1);
            srcs[p] = (ushort)(r & 0xFFFFu);
        }
    }
}

// ---------------- GEMM body: MFMA split-bf16 (hi+lo), frag-ordered W -------------
// Block 256 thr = 4 waves; wave = 16 rows x 128 cols.
// H2: packed bf16x2, word l = {f_l, f_{l+64}}; es2[n] = {es, ed} (float2).
template <int K, bool AF32>
__device__ __forceinline__ void gemm_body(
    int bid, const void* __restrict__ A, const ushort* __restrict__ wt,
    unsigned* __restrict__ H2, const int* __restrict__ flags,
    const void* __restrict__ aS, const void* __restrict__ aD,
    float2* __restrict__ es2, short8* sB8) {
    constexpr int NC = K / 32;
    int wave = threadIdx.x >> 6, lane = threadIdx.x & 63;
    int quad = lane >> 4, n16 = lane & 15;
    int rb = bid * 64 + wave * 16;
    int rowa = min(rb + n16, N_NODES - 1);
    f32x4 acc[8];
#pragma unroll
    for (int t = 0; t < 8; t++) acc[t] = (f32x4){0.f, 0.f, 0.f, 0.f};

    for (int c = 0; c < NC; c++) {
#pragma unroll
        for (int i = 0; i < 4; i++) {
            int fw = wave * 4 + i;
            stage16(wt + ((size_t)c * 16 + fw) * 512 + lane * 8, &sB8[fw * 64]);
        }
        float av[8];
        if (AF32) {
            const float* ap = (const float*)A + (size_t)rowa * K + c * 32 + quad * 8;
            f32x4 a0 = *(const f32x4*)ap;
            f32x4 a1 = *(const f32x4*)(ap + 4);
#pragma unroll
            for (int j = 0; j < 4; j++) { av[j] = a0[j]; av[j + 4] = a1[j]; }
        } else {
            const ushort* ap = (const ushort*)A + (size_t)rowa * K + c * 32 + quad * 8;
#pragma unroll
            for (int j = 0; j < 8; j++) av[j] = bf2f(ap[j]);
        }
        short8 ahi, alo;
#pragma unroll
        for (int j = 0; j < 8; j++) {
            ushort h = f2bf(av[j]);
            ahi[j] = (short)h;
            alo[j] = (short)f2bf(av[j] - bf2f(h));
        }
        __syncthreads();   // staging complete
#pragma unroll
        for (int nt = 0; nt < 8; nt++) {
            short8 bh = sB8[(nt * 2 + 0) * 64 + lane];
            short8 bl = sB8[(nt * 2 + 1) * 64 + lane];
            acc[nt] = __builtin_amdgcn_mfma_f32_16x16x32_bf16(ahi, bh, acc[nt], 0, 0, 0);
            acc[nt] = __builtin_amdgcn_mfma_f32_16x16x32_bf16(ahi, bl, acc[nt], 0, 0, 0);
            acc[nt] = __builtin_amdgcn_mfma_f32_16x16x32_bf16(alo, bh, acc[nt], 0, 0, 0);
        }
        __syncthreads();
    }

    // epilogue: packed-bf16 H2 store + fused ead (es2 = {h.as, h.ad})
    int f32 = flags[0];
    float asv[8], adv[8];
#pragma unroll
    for (int nt = 0; nt < 8; nt++) {
        asv[nt] = ldf(aS, nt * 16 + n16, f32);
        adv[nt] = ldf(aD, nt * 16 + n16, f32);
    }
#pragma unroll
    for (int r = 0; r < 4; r++) {
        int ro = rb + quad * 4 + r;
        float s = 0.f, dv = 0.f;
#pragma unroll
        for (int nt = 0; nt < 8; nt++) {
            s += acc[nt][r] * asv[nt];
            dv += acc[nt][r] * adv[nt];
        }
        if (ro < N_NODES) {
#pragma unroll
            for (int nt = 0; nt < 4; nt++) {   // word c = {f_c, f_{c+64}}
                unsigned pack = (unsigned)f2bf(acc[nt][r]) |
                                ((unsigned)f2bf(acc[nt + 4][r]) << 16);
                H2[(size_t)ro * 64 + nt * 16 + n16] = pack;
            }
        }
#pragma unroll
        for (int off = 8; off; off >>= 1) {
            s += __shfl_xor(s, off);
            dv += __shfl_xor(dv, off);
        }
        if (n16 == 0 && ro < N_NODES) es2[ro] = make_float2(s, dv);
    }
}

// hybrid dispatch: blocks [0,NBUCK) run binB; blocks [NBUCK, NBUCK+gemm_grid)
// run layer-1 GEMM (independent work, same stream slot).
template <int K>
__global__ __launch_bounds__(256, 3) void binB_gemm_kernel(
    const unsigned* __restrict__ pairs, const int* __restrict__ cnts,
    int2* __restrict__ rowse, ushort* __restrict__ srcs,
    const void* __restrict__ A, const ushort* __restrict__ wt,
    unsigned* __restrict__ H2, const int* __restrict__ flags,
    const void* __restrict__ aS, const void* __restrict__ aD,
    float2* __restrict__ es2) {
    __shared__ short8 sB8[16 * 64];   // 16 KB (gemm blocks)
    __shared__ int s_cnt[256], s_cur[256], s_ccnt[NBA];
    if (blockIdx.x < NBUCK) {
        binB_body(pairs, cnts, rowse, srcs, blockIdx.x, threadIdx.x,
                  s_cnt, s_cur, s_ccnt);
        return;
    }
    int bid = blockIdx.x - NBUCK;
    if (flags[0]) gemm_body<K, true>(bid, A, wt, H2, flags, aS, aD, es2, sB8);
    else          gemm_body<K, false>(bid, A, wt, H2, flags, aS, aD, es2, sB8);
}

// standalone layer-2 GEMM (a_mode 2: internal bf16 A); block 0 zeroes gsum for
// the following fused agg+pool dispatch.
template <int K>
__global__ __launch_bounds__(256, 3) void gemm_mfma_kernel(
    const void* __restrict__ A, const ushort* __restrict__ wt,
    unsigned* __restrict__ H2, int a_mode, const int* __restrict__ flags,
    const void* __restrict__ aS, const void* __restrict__ aD,
    float2* __restrict__ es2, float* __restrict__ zbuf) {
    __shared__ short8 sB8[16 * 64];
    if (zbuf != nullptr && blockIdx.x == 0) {
        for (int i = threadIdx.x; i < NGRAPH * G; i += 256) zbuf[i] = 0.f;
    }
    int af32 = (a_mode == 2) ? 0 : flags[0];   // block-uniform
    if (af32) gemm_body<K, true>(blockIdx.x, A, wt, H2, flags, aS, aD, es2, sB8);
    else      gemm_body<K, false>(blockIdx.x, A, wt, H2, flags, aS, aD, es2, sB8);
}

// Fused GAT aggregate v6: QUARTER-WAVE nodes. Round-4 evidence: 1-node/wave was
// latency-bound (dur 155us, VALU 18%, HBM 9%, nothing saturated) with only
// 32B/lane of gather in flight. Now each 16-lane group owns one node; a gathered
// h2 row (256B) is read as 16 lanes x uint4 (16B) -> 4x bytes-in-flight/lane,
// and the softmax phase matches degree~17 with 16 lanes instead of 64.
// 50000 = 3125 blocks x 16 nodes exactly (no tail). (s,p) broadcast via
// group-local __shfl; reductions via xor 8/4/2/1.
template <int POOL>
__global__ __launch_bounds__(256) void gat_agg_kernel(
    const unsigned* __restrict__ h2, const int2* __restrict__ rowse,
    const ushort* __restrict__ srcs, const float2* __restrict__ es2,
    const void* __restrict__ bias, ushort* __restrict__ outb,
    const void* __restrict__ batch, float* __restrict__ gsum,
    const int* __restrict__ flags) {
    int l = threadIdx.x & 63;
    int lq = l & 15;                       // lane within group
    int gb = l & 48;                       // group base lane within wave
    int node = blockIdx.x * 16 + (threadIdx.x >> 4);
    int2 se = rowse[node];
    int start = se.x, end = se.y;
    float edd = es2[node].y;
    float m = -INFINITY, den = 0.f;
    f32x4 accL = (f32x4){0.f, 0.f, 0.f, 0.f};
    f32x4 accH = (f32x4){0.f, 0.f, 0.f, 0.f};
    for (int c0 = start; c0 < end; c0 += 16) {
        int cn = min(end - c0, 16);
        int s = 0; float v = -INFINITY;
        if (lq < cn) {
            s = (int)srcs[c0 + lq];
            v = es2[s].x + edd;
            v = v >= 0.f ? v : 0.2f * v;    // LeakyReLU(0.2)
        }
        float mc = v;
#pragma unroll
        for (int off = 8; off; off >>= 1) mc = fmaxf(mc, __shfl_xor(mc, off));
        float mnew = fmaxf(m, mc);
        float scale = expf(m - mnew);        // m=-INF first chunk -> 0
        float p = (lq < cn) ? expf(v - mnew) : 0.f;
        float lsum = p;
#pragma unroll
        for (int off = 8; off; off >>= 1) lsum += __shfl_xor(lsum, off);
        den = den * scale + lsum;
#pragma unroll
        for (int k = 0; k < 4; k++) { accL[k] *= scale; accH[k] *= scale; }
        int cnr = (cn + 7) & ~7;             // 8 or 16; tail lanes have p=0, s=0
        for (int i = 0; i < cnr; i += 8) {
            int sis[8]; float pis[8]; u32x4 hv[8];
#pragma unroll
            for (int j = 0; j < 8; j++) {
                sis[j] = __shfl(s, gb + i + j);
                pis[j] = __shfl(p, gb + i + j);
            }
#pragma unroll
            for (int j = 0; j < 8; j++)      // 8 outstanding 16B-lane gathers
                hv[j] = *((const u32x4*)(h2 + (size_t)sis[j] * 64) + lq);
#pragma unroll
            for (int j = 0; j < 8; j++) {
#pragma unroll
                for (int k = 0; k < 4; k++) {
                    unsigned w = hv[j][k];
                    accL[k] += pis[j] * bf2f((ushort)(w & 0xFFFFu));
                    accH[k] += pis[j] * bf2f((ushort)(w >> 16));
                }
            }
        }
        m = mnew;
    }
    float inv = 1.f / (den + 1e-16f);
    int f32 = flags[0];
    // lane lq owns features c = lq*4+k and c+64
    if (POOL) {
        int gid = min(max(ldi(batch, node, flags[1]), 0), NGRAPH - 1);
#pragma unroll
        for (int k = 0; k < 4; k++) {
            int c = lq * 4 + k;
            atomicAdd(&gsum[gid * G + c],      selu_f(accL[k] * inv + ldf(bias, c, f32)));
            atomicAdd(&gsum[gid * G + 64 + c], selu_f(accH[k] * inv + ldf(bias, 64 + c, f32)));
        }
    } else {
        s16x4 oL, oH;
#pragma unroll
        for (int k = 0; k < 4; k++) {
            int c = lq * 4 + k;
            oL[k] = (short)f2bf(selu_f(accL[k] * inv + ldf(bias, c, f32)));
            oH[k] = (short)f2bf(selu_f(accH[k] * inv + ldf(bias, 64 + c, f32)));
        }
        *(s16x4*)(outb + (size_t)node * G + lq * 4)      = oL;
        *(s16x4*)(outb + (size_t)node * G + 64 + lq * 4) = oH;
    }
}

// pooled -> selu -> lin1+selu -> lin2 -> log_softmax; counts via binary search
// over the sorted batch vector. OUTPUT FLOAT32.
__global__ void head_kernel(const float* __restrict__ gsum, const void* __restrict__ batch,
                            const void* __restrict__ lw1, const void* __restrict__ lb1,
                            const void* __restrict__ lw2, const void* __restrict__ lb2,
                            float* __restrict__ out, const int* __restrict__ flags) {
    int g = blockIdx.x, t = threadIdx.x;  // 64
    int f32 = flags[0], i64 = flags[1];
    __shared__ float z[G];
    __shared__ float z1[NHID];
    __shared__ float z2[2];
    __shared__ int sb[2];
    if (t < 2) {                       // lower_bound(g), lower_bound(g+1)
        int target = g + t;
        int lo = 0, hi = N_NODES;
        while (lo < hi) {
            int mid = (lo + hi) >> 1;
            int v = ldi(batch, mid, i64);
            if (v < target) lo = mid + 1; else hi = mid;
        }
        sb[t] = lo;
    }
    __syncthreads();
    float cnt = fmaxf((float)(sb[1] - sb[0]), 1.0f);
    z[t]      = selu_f(gsum[g * G + t] / cnt);
    z[t + 64] = selu_f(gsum[g * G + 64 + t] / cnt);
    __syncthreads();
    float a = ldf(lb1, t, f32);
    for (int k = 0; k < G; k++) a += z[k] * ldf(lw1, k * NHID + t, f32);
    z1[t] = selu_f(a);
    __syncthreads();
    if (t < 2) {
        float s = ldf(lb2, t, f32);
        for (int j = 0; j < NHID; j++) s += z1[j] * ldf(lw2, j * 2 + t, f32);
        z2[t] = s;
    }
    __syncthreads();
    if (t == 0) {
        float mx = fmaxf(z2[0], z2[1]);
        float l = mx + logf(expf(z2[0] - mx) + expf(z2[1] - mx));
        out[g * 2 + 0] = z2[0] - l;
        out[g * 2 + 1] = z2[1] - l;
    }
}

extern "C" void kernel_launch(void* const* d_in, const int* in_sizes, int n_in,
                              void* d_out, int out_size, void* d_ws, size_t ws_size,
                              hipStream_t stream) {
    const void* x    = d_in[0];
    const void* ei   = d_in[1];
    const void* batch= d_in[2];
    const void* W1   = d_in[3];
    const void* as1  = d_in[4];
    const void* ad1  = d_in[5];
    const void* b1   = d_in[6];
    const void* W2   = d_in[7];
    const void* as2  = d_in[8];
    const void* ad2  = d_in[9];
    const void* b2   = d_in[10];
    const void* lw1  = d_in[11];
    const void* lb1  = d_in[12];
    const void* lw2  = d_in[13];
    const void* lb2  = d_in[14];
    float* out = (float*)d_out;

    char* w = (char*)d_ws;
    size_t off = 0;
    auto alloc = [&](size_t bytes) -> char* {
        char* p = w + off;
        off = (off + bytes + 255) & ~(size_t)255;
        return p;
    };
    int*      flags  = (int*)alloc(256);
    unsigned* h2     = (unsigned*)alloc((size_t)N_NODES * 64 * 4);  // packed bf16x2
    ushort*   abuf   = (ushort*)alloc((size_t)N_NODES * G * 2);     // bf16 L1 output
    float2*   es2    = (float2*)alloc((size_t)N_NODES * 8);
    int2*     rowse  = (int2*)alloc((size_t)N_NODES * 8);
    unsigned* pairs  = (unsigned*)alloc((size_t)NBUCK * NBA * CELL * 4);  // 9.8 MB
    int*      cnts   = (int*)alloc((size_t)NBUCK * NBA * 4);
    ushort*   srcs   = (ushort*)alloc((size_t)NBUCK * CAPB * 2);
    float*    gsum   = (float*)alloc((size_t)NGRAPH * G * 4);
    ushort*   wt1    = (ushort*)alloc((size_t)IN_F * G * 2 * 2);   // hi+lo frag-ordered
    ushort*   wt2    = (ushort*)alloc((size_t)G * G * 2 * 2);

    unsigned gemm_grid = (N_NODES + 63) / 64;   // 782
    unsigned agg_grid = N_NODES / 16;           // 3125 (exact)

    // 1. edge bucketing (+ inline dtype detect, flags publish, fused wt)
    binA_kernel<<<NBA, 256, 0, stream>>>(ei, pairs, cnts, flags, x, W1, W2, wt1, wt2);
    // 2. hybrid: binB (CSR finalize + self-loops) + layer-1 GEMM
    binB_gemm_kernel<IN_F><<<NBUCK + gemm_grid, 256, 0, stream>>>(
        pairs, cnts, rowse, srcs, x, wt1, h2, flags, as1, ad1, es2);
    // 3. layer-1 aggregate -> abuf
    gat_agg_kernel<0><<<agg_grid, 256, 0, stream>>>(h2, rowse, srcs, es2, b1, abuf,
                                                    nullptr, nullptr, flags);
    // 4. layer-2 GEMM (+ gsum zero by block 0)
    gemm_mfma_kernel<G><<<gemm_grid, 256, 0, stream>>>(abuf, wt2, h2, 2, flags,
                                                       as2, ad2, es2, gsum);
    // 5. layer-2 aggregate + fused global_mean_pool (atomic gsum)
    gat_agg_kernel<1><<<agg_grid, 256, 0, stream>>>(h2, rowse, srcs, es2, b2, nullptr,
                                                    batch, gsum, flags);
    // 6. head (counts via binary search on sorted batch)
    head_kernel<<<NGRAPH, 64, 0, stream>>>(gsum, batch, lw1, lb1, lw2, lb2, out, flags);
}

// Round 6
// 351.275 us; speedup vs baseline: 1.8348x; 1.8348x over previous
//
#include <hip/hip_runtime.h>
#include <hip/hip_bf16.h>
#include <math.h>

#define N_NODES 50000
#define N_EDGES 800000
#define IN_F 256
#define G 128                    // 2*HID
#define NHID 64
#define NGRAPH 32
#define NBUCK ((N_NODES + 255) / 256)    // 196 buckets (dst>>8)
#define CAPB 8192                         // srcs capacity per bucket (mean 4352+256)
#define CELL 64                           // pairs capacity per (bucket, binA-block)
#define EPB 4096                          // edges per binA block
#define NBA ((N_EDGES + EPB - 1) / EPB)   // 196 (real edges only; self-loops direct)

typedef __hip_bfloat16 bf16;
typedef unsigned short ushort;
typedef __attribute__((ext_vector_type(8))) short short8;
typedef __attribute__((ext_vector_type(4))) float f32x4;

// ---------- dtype-agnostic loads ----------
__device__ __forceinline__ float bf2f(ushort u) {
    union { unsigned u; float f; } c; c.u = ((unsigned)u) << 16; return c.f;
}
// round-to-nearest-even f32 -> bf16 (finite inputs)
__device__ __forceinline__ ushort f2bf(float f) {
    unsigned u = __float_as_uint(f);
    u += 0x7FFFu + ((u >> 16) & 1u);
    return (ushort)(u >> 16);
}
__device__ __forceinline__ float ldf(const void* p, long i, int f32) {
    return f32 ? ((const float*)p)[i] : bf2f(((const ushort*)p)[i]);
}
__device__ __forceinline__ int ldi(const void* p, long i, int i64) {
    return i64 ? (int)((const long long*)p)[i] : ((const int*)p)[i];
}

__device__ __forceinline__ float selu_f(float x) {
    const float sc = 1.0507009873554805f, al = 1.6732632423543772f;
    return x > 0.f ? sc * x : sc * al * expm1f(x);
}

// async global->LDS, 16 B/lane; lds base must be wave-uniform.
typedef const __attribute__((address_space(1))) void gas_void;
typedef __attribute__((address_space(3))) void las_void;
__device__ __forceinline__ void stage16(const void* g, void* l) {
    __builtin_amdgcn_global_load_lds((gas_void*)g, (las_void*)l, 16, 0, 0);
}

__device__ __forceinline__ void edge_sd(const void* __restrict__ ei, int e, int i64,
                                        int& s, int& d) {
    s = ldi(ei, e, i64);
    d = ldi(ei, (long)N_EDGES + e, i64);
    s = min(max(s, 0), N_NODES - 1);
    d = min(max(d, 0), N_NODES - 1);
}

// ---------------- CSR build v5: cells + direct self-loop insertion ---------------
// binA block k writes bucket-b records to cell (b,k), CELL=64 capacity. Only the
// 800K REAL edges stream through binA (Poisson(21)/cell -> P(>64)~1e-14); the
// 50K self-loops are inserted deterministically by binB at slot 0 of each node's
// range. cnts[b][k] fully overwritten -> no pre-zeroing. Inline dtype detect;
// fused wt.

__global__ __launch_bounds__(256) void binA_kernel(
    const void* __restrict__ ei, unsigned* __restrict__ pairs,
    int* __restrict__ cnts, int* __restrict__ flags,
    const void* __restrict__ x,
    const void* __restrict__ W1, const void* __restrict__ W2,
    ushort* __restrict__ wt1, ushort* __restrict__ wt2) {
    __shared__ int cnt[256], lofs[256], pcur[256];
    __shared__ unsigned stage[EPB];
    __shared__ int s_i64, s_f32;
    int t = threadIdx.x;

    // ---- inline dtype detect: wave0 -> i64 flag, wave1 -> f32 flag ----
    if (t < 64) {
        const unsigned* wu = (const unsigned*)ei;
        long j = 1 + (long)t * 24986;           // odd dwords, < 1.6M (int32-safe)
        unsigned long long bal = __ballot(wu[j] != 0u);
        if (t == 0) s_i64 = (__popcll(bal) < 16) ? 1 : 0;   // i64: high words all 0
    } else if (t < 128) {
        const unsigned* xu = (const unsigned*)x;
        unsigned u = xu[(long)(t - 64) * 100000];           // < 6.4M dwords (bf16-safe)
        unsigned e = (u >> 23) & 0xFF;
        unsigned long long bal = __ballot(u == 0u || (e >= 100 && e <= 140));
        if (t == 64) s_f32 = (__popcll(bal) >= 32) ? 1 : 0;
    }
    cnt[t] = 0;
    __syncthreads();
    int i64 = s_i64, f32 = s_f32;
    if (blockIdx.x == 0 && t == 0) { flags[0] = f32; flags[1] = i64; }

    int e0 = blockIdx.x * EPB;
    int nE = min(EPB, N_EDGES - e0);
    int sj[EPB / 256], dj[EPB / 256];
#pragma unroll
    for (int j = 0; j < EPB / 256; j++) {
        int idx = j * 256 + t;
        if (idx < nE) {
            edge_sd(ei, e0 + idx, i64, sj[j], dj[j]);
            atomicAdd(&cnt[dj[j] >> 8], 1);
        } else dj[j] = -1;
    }
    __syncthreads();
    lofs[t] = cnt[t];
    for (int off = 1; off < 256; off <<= 1) {
        __syncthreads();
        int v = (t >= off) ? lofs[t - off] : 0;
        __syncthreads();
        lofs[t] += v;
    }
    __syncthreads();
    int excl = lofs[t] - cnt[t];
    __syncthreads();
    lofs[t] = excl;
    pcur[t] = excl;
    __syncthreads();
#pragma unroll
    for (int j = 0; j < EPB / 256; j++) {
        if (dj[j] >= 0) {
            int b = dj[j] >> 8;
            int lp = atomicAdd(&pcur[b], 1);
            stage[lp] = (unsigned)sj[j] | ((unsigned)(dj[j] & 255) << 16) |
                        ((unsigned)b << 24);
        }
    }
    __syncthreads();
    for (int i = t; i < nE; i += 256) {      // per-bucket contiguous cell writes
        unsigned p = stage[i];
        int b = p >> 24;
        int off2 = i - lofs[b];
        if (off2 < CELL)
            pairs[((size_t)b * NBA + blockIdx.x) * CELL + off2] = p;
    }
    if (t < NBUCK) cnts[(size_t)t * NBA + blockIdx.x] = min(cnt[t], CELL);

    // ---- fused wt: split-bf16 (hi+lo) frag-reorder of W1,W2 (NBA*256 >= 49152) --
    int wi = blockIdx.x * 256 + t;
    if (wi < IN_F * G + G * G) {
        const void* W; ushort* wtp; int idx;
        if (wi < IN_F * G) { W = W1; wtp = wt1; idx = wi; }
        else { W = W2; wtp = wt2; idx = wi - IN_F * G; }
        int k = idx >> 7, n = idx & (G - 1);
        float wv = ldf(W, idx, f32);
        ushort h = f2bf(wv);
        ushort lo = f2bf(wv - bf2f(h));
        int c = k >> 5, q = (k >> 3) & 3, j = k & 7;
        int nt = n >> 4, n16 = n & 15;
        int lane = q * 16 + n16;
        size_t base = ((size_t)c * 16 + nt * 2) * 512 + lane * 8 + j;
        wtp[base] = h;           // hilo = 0
        wtp[base + 512] = lo;    // hilo = 1
    }
}

// binB: per-bucket node count/scan -> rowse, self-loop at slot 0, scatter cells.
__device__ __forceinline__ void binB_body(
    const unsigned* __restrict__ pairs, const int* __restrict__ cnts,
    int2* __restrict__ rowse, ushort* __restrict__ srcs,
    int b, int t, int* cnt, int* cur, int* ccnt) {
    if (t < NBA) ccnt[t] = cnts[(size_t)b * NBA + t];
    int node = b * 256 + t;
    int valid = (node < N_NODES) ? 1 : 0;
    cnt[t] = valid;                        // reserve the self-loop slot
    __syncthreads();
    if (t < NBA) {                         // thread t streams cell (b,t), 4-batched
        const unsigned* cp = pairs + ((size_t)b * NBA + t) * CELL;
        int n = ccnt[t], i = 0;
        for (; i + 4 <= n; i += 4) {
            unsigned r0 = cp[i], r1 = cp[i + 1], r2 = cp[i + 2], r3 = cp[i + 3];
            atomicAdd(&cnt[(r0 >> 16) & 255], 1);
            atomicAdd(&cnt[(r1 >> 16) & 255], 1);
            atomicAdd(&cnt[(r2 >> 16) & 255], 1);
            atomicAdd(&cnt[(r3 >> 16) & 255], 1);
        }
        for (; i < n; i++) atomicAdd(&cnt[(cp[i] >> 16) & 255], 1);
    }
    __syncthreads();
    cur[t] = cnt[t];
    for (int off = 1; off < 256; off <<= 1) {
        __syncthreads();
        int v = (t >= off) ? cur[t - off] : 0;
        __syncthreads();
        cur[t] += v;
    }
    int excl = cur[t] - cnt[t];
    int base = b * CAPB;
    int myCnt = cnt[t];
    __syncthreads();
    if (valid) {
        srcs[base + excl] = (ushort)node;  // self-loop at slot 0
        rowse[node] = make_int2(base + excl, base + excl + myCnt);
    }
    cur[t] = base + excl + valid;
    __syncthreads();
    if (t < NBA) {
        const unsigned* cp = pairs + ((size_t)b * NBA + t) * CELL;
        int n = ccnt[t], i = 0;
        for (; i + 4 <= n; i += 4) {
            unsigned r0 = cp[i], r1 = cp[i + 1], r2 = cp[i + 2], r3 = cp[i + 3];
            int p0 = atomicAdd(&cur[(r0 >> 16) & 255], 1);
            int p1 = atomicAdd(&cur[(r1 >> 16) & 255], 1);
            int p2 = atomicAdd(&cur[(r2 >> 16) & 255], 1);
            int p3 = atomicAdd(&cur[(r3 >> 16) & 255], 1);
            srcs[p0] = (ushort)(r0 & 0xFFFFu);
            srcs[p1] = (ushort)(r1 & 0xFFFFu);
            srcs[p2] = (ushort)(r2 & 0xFFFFu);
            srcs[p3] = (ushort)(r3 & 0xFFFFu);
        }
        for (; i < n; i++) {
            unsigned r = cp[i];
            int p = atomicAdd(&cur[(r >> 16) & 255], 1);
            srcs[p] = (ushort)(r & 0xFFFFu);
        }
    }
}

// ---------------- GEMM body: MFMA split-bf16 (hi+lo), frag-ordered W -------------
// Block 256 thr = 4 waves; wave = 16 rows x 128 cols.
// H2: packed bf16x2, word l = {f_l, f_{l+64}}; es2[n] = {es, ed} (float2).
template <int K, bool AF32>
__device__ __forceinline__ void gemm_body(
    int bid, const void* __restrict__ A, const ushort* __restrict__ wt,
    unsigned* __restrict__ H2, const int* __restrict__ flags,
    const void* __restrict__ aS, const void* __restrict__ aD,
    float2* __restrict__ es2, short8* sB8) {
    constexpr int NC = K / 32;
    int wave = threadIdx.x >> 6, lane = threadIdx.x & 63;
    int quad = lane >> 4, n16 = lane & 15;
    int rb = bid * 64 + wave * 16;
    int rowa = min(rb + n16, N_NODES - 1);
    f32x4 acc[8];
#pragma unroll
    for (int t = 0; t < 8; t++) acc[t] = (f32x4){0.f, 0.f, 0.f, 0.f};

    for (int c = 0; c < NC; c++) {
#pragma unroll
        for (int i = 0; i < 4; i++) {
            int fw = wave * 4 + i;
            stage16(wt + ((size_t)c * 16 + fw) * 512 + lane * 8, &sB8[fw * 64]);
        }
        float av[8];
        if (AF32) {
            const float* ap = (const float*)A + (size_t)rowa * K + c * 32 + quad * 8;
            f32x4 a0 = *(const f32x4*)ap;
            f32x4 a1 = *(const f32x4*)(ap + 4);
#pragma unroll
            for (int j = 0; j < 4; j++) { av[j] = a0[j]; av[j + 4] = a1[j]; }
        } else {
            const ushort* ap = (const ushort*)A + (size_t)rowa * K + c * 32 + quad * 8;
#pragma unroll
            for (int j = 0; j < 8; j++) av[j] = bf2f(ap[j]);
        }
        short8 ahi, alo;
#pragma unroll
        for (int j = 0; j < 8; j++) {
            ushort h = f2bf(av[j]);
            ahi[j] = (short)h;
            alo[j] = (short)f2bf(av[j] - bf2f(h));
        }
        __syncthreads();   // staging complete
#pragma unroll
        for (int nt = 0; nt < 8; nt++) {
            short8 bh = sB8[(nt * 2 + 0) * 64 + lane];
            short8 bl = sB8[(nt * 2 + 1) * 64 + lane];
            acc[nt] = __builtin_amdgcn_mfma_f32_16x16x32_bf16(ahi, bh, acc[nt], 0, 0, 0);
            acc[nt] = __builtin_amdgcn_mfma_f32_16x16x32_bf16(ahi, bl, acc[nt], 0, 0, 0);
            acc[nt] = __builtin_amdgcn_mfma_f32_16x16x32_bf16(alo, bh, acc[nt], 0, 0, 0);
        }
        __syncthreads();
    }

    // epilogue: packed-bf16 H2 store + fused ead (es2 = {h.as, h.ad})
    int f32 = flags[0];
    float asv[8], adv[8];
#pragma unroll
    for (int nt = 0; nt < 8; nt++) {
        asv[nt] = ldf(aS, nt * 16 + n16, f32);
        adv[nt] = ldf(aD, nt * 16 + n16, f32);
    }
#pragma unroll
    for (int r = 0; r < 4; r++) {
        int ro = rb + quad * 4 + r;
        float s = 0.f, dv = 0.f;
#pragma unroll
        for (int nt = 0; nt < 8; nt++) {
            s += acc[nt][r] * asv[nt];
            dv += acc[nt][r] * adv[nt];
        }
        if (ro < N_NODES) {
#pragma unroll
            for (int nt = 0; nt < 4; nt++) {   // word c = {f_c, f_{c+64}}
                unsigned pack = (unsigned)f2bf(acc[nt][r]) |
                                ((unsigned)f2bf(acc[nt + 4][r]) << 16);
                H2[(size_t)ro * 64 + nt * 16 + n16] = pack;
            }
        }
#pragma unroll
        for (int off = 8; off; off >>= 1) {
            s += __shfl_xor(s, off);
            dv += __shfl_xor(dv, off);
        }
        if (n16 == 0 && ro < N_NODES) es2[ro] = make_float2(s, dv);
    }
}

// hybrid dispatch: blocks [0,NBUCK) run binB; blocks [NBUCK, NBUCK+gemm_grid)
// run layer-1 GEMM (independent work, same stream slot).
template <int K>
__global__ __launch_bounds__(256, 3) void binB_gemm_kernel(
    const unsigned* __restrict__ pairs, const int* __restrict__ cnts,
    int2* __restrict__ rowse, ushort* __restrict__ srcs,
    const void* __restrict__ A, const ushort* __restrict__ wt,
    unsigned* __restrict__ H2, const int* __restrict__ flags,
    const void* __restrict__ aS, const void* __restrict__ aD,
    float2* __restrict__ es2) {
    __shared__ short8 sB8[16 * 64];   // 16 KB (gemm blocks)
    __shared__ int s_cnt[256], s_cur[256], s_ccnt[NBA];
    if (blockIdx.x < NBUCK) {
        binB_body(pairs, cnts, rowse, srcs, blockIdx.x, threadIdx.x,
                  s_cnt, s_cur, s_ccnt);
        return;
    }
    int bid = blockIdx.x - NBUCK;
    if (flags[0]) gemm_body<K, true>(bid, A, wt, H2, flags, aS, aD, es2, sB8);
    else          gemm_body<K, false>(bid, A, wt, H2, flags, aS, aD, es2, sB8);
}

// standalone layer-2 GEMM (a_mode 2: internal bf16 A); block 0 zeroes gsum for
// the following fused agg+pool dispatch.
template <int K>
__global__ __launch_bounds__(256, 3) void gemm_mfma_kernel(
    const void* __restrict__ A, const ushort* __restrict__ wt,
    unsigned* __restrict__ H2, int a_mode, const int* __restrict__ flags,
    const void* __restrict__ aS, const void* __restrict__ aD,
    float2* __restrict__ es2, float* __restrict__ zbuf) {
    __shared__ short8 sB8[16 * 64];
    if (zbuf != nullptr && blockIdx.x == 0) {
        for (int i = threadIdx.x; i < NGRAPH * G; i += 256) zbuf[i] = 0.f;
    }
    int af32 = (a_mode == 2) ? 0 : flags[0];   // block-uniform
    if (af32) gemm_body<K, true>(blockIdx.x, A, wt, H2, flags, aS, aD, es2, sB8);
    else      gemm_body<K, false>(blockIdx.x, A, wt, H2, flags, aS, aD, es2, sB8);
}

// Fused GAT aggregate v7: r4 structure (1 node/wave, readlane broadcast -> SGPR
// edge state, scalar 4B gather, VGPR<=64) with batch depth 16 (was 8).
// Round-5 lesson: __shfl-based broadcast puts sis/pis in VGPRs -> spill ->
// scratch thrash (WRITE 100MB, 3x slower). readlane keeps them in SGPRs.
// Depth 16 halves the sequential-batch count for mean degree ~17
// (one 16-batch + one 8-batch instead of 3x 8-batch).
template <int POOL>
__global__ __launch_bounds__(256) void gat_agg_kernel(
    const unsigned* __restrict__ h2, const int2* __restrict__ rowse,
    const ushort* __restrict__ srcs, const float2* __restrict__ es2,
    const void* __restrict__ bias, ushort* __restrict__ outb,
    const void* __restrict__ batch, float* __restrict__ gsum,
    const int* __restrict__ flags) {
    int node = blockIdx.x * 4 + (threadIdx.x >> 6);
    if (node >= N_NODES) return;            // wave-uniform
    int l = threadIdx.x & 63;
    int2 se = rowse[node];
    int start = se.x, end = se.y;
    float edd = es2[node].y;
    float m = -INFINITY, den = 0.f;
    float acc0 = 0.f, acc1 = 0.f;
    for (int c0 = start; c0 < end; c0 += 64) {
        int cn = min(end - c0, 64);
        int s = 0; float v = -INFINITY;
        if (l < cn) {
            s = (int)srcs[c0 + l];
            v = es2[s].x + edd;
            v = v >= 0.f ? v : 0.2f * v;    // LeakyReLU(0.2)
        }
        float mc = v;
#pragma unroll
        for (int off = 32; off; off >>= 1) mc = fmaxf(mc, __shfl_xor(mc, off));
        float mnew = fmaxf(m, mc);
        float scale = expf(m - mnew);        // m=-INF first chunk -> 0
        float p = (l < cn) ? expf(v - mnew) : 0.f;
        float lsum = p;
#pragma unroll
        for (int off = 32; off; off >>= 1) lsum += __shfl_xor(lsum, off);
        den = den * scale + lsum;
        acc0 *= scale; acc1 *= scale;
        int cnr = (cn + 7) & ~7;             // multiple of 8; tail lanes p=0
        int i = 0;
        for (; i + 16 <= cnr; i += 16) {     // 16-deep batches
            int sis[16]; float pis[16]; unsigned hv[16];
#pragma unroll
            for (int j = 0; j < 16; j++)
                sis[j] = __builtin_amdgcn_readlane(s, i + j);
#pragma unroll
            for (int j = 0; j < 16; j++)     // 16 outstanding 256B wave-loads
                hv[j] = h2[(size_t)sis[j] * 64 + l];
#pragma unroll
            for (int j = 0; j < 16; j++)
                pis[j] = __uint_as_float(
                    __builtin_amdgcn_readlane(__float_as_uint(p), i + j));
#pragma unroll
            for (int j = 0; j < 16; j++) {
                acc0 += pis[j] * bf2f((ushort)(hv[j] & 0xFFFFu));
                acc1 += pis[j] * bf2f((ushort)(hv[j] >> 16));
            }
        }
        if (i < cnr) {                       // exactly one 8-batch tail
            int sis[8]; float pis[8]; unsigned hv[8];
#pragma unroll
            for (int j = 0; j < 8; j++)
                sis[j] = __builtin_amdgcn_readlane(s, i + j);
#pragma unroll
            for (int j = 0; j < 8; j++)
                hv[j] = h2[(size_t)sis[j] * 64 + l];
#pragma unroll
            for (int j = 0; j < 8; j++)
                pis[j] = __uint_as_float(
                    __builtin_amdgcn_readlane(__float_as_uint(p), i + j));
#pragma unroll
            for (int j = 0; j < 8; j++) {
                acc0 += pis[j] * bf2f((ushort)(hv[j] & 0xFFFFu));
                acc1 += pis[j] * bf2f((ushort)(hv[j] >> 16));
            }
        }
        m = mnew;
    }
    float inv = 1.f / (den + 1e-16f);
    int f32 = flags[0];
    float o0 = selu_f(acc0 * inv + ldf(bias, l, f32));
    float o1 = selu_f(acc1 * inv + ldf(bias, l + 64, f32));
    if (POOL) {
        int gid = min(max(ldi(batch, node, flags[1]), 0), NGRAPH - 1);
        atomicAdd(&gsum[gid * G + l], o0);
        atomicAdd(&gsum[gid * G + 64 + l], o1);
    } else {
        outb[(size_t)node * G + l]      = f2bf(o0);
        outb[(size_t)node * G + l + 64] = f2bf(o1);
    }
}

// pooled -> selu -> lin1+selu -> lin2 -> log_softmax; counts via binary search
// over the sorted batch vector. OUTPUT FLOAT32.
__global__ void head_kernel(const float* __restrict__ gsum, const void* __restrict__ batch,
                            const void* __restrict__ lw1, const void* __restrict__ lb1,
                            const void* __restrict__ lw2, const void* __restrict__ lb2,
                            float* __restrict__ out, const int* __restrict__ flags) {
    int g = blockIdx.x, t = threadIdx.x;  // 64
    int f32 = flags[0], i64 = flags[1];
    __shared__ float z[G];
    __shared__ float z1[NHID];
    __shared__ float z2[2];
    __shared__ int sb[2];
    if (t < 2) {                       // lower_bound(g), lower_bound(g+1)
        int target = g + t;
        int lo = 0, hi = N_NODES;
        while (lo < hi) {
            int mid = (lo + hi) >> 1;
            int v = ldi(batch, mid, i64);
            if (v < target) lo = mid + 1; else hi = mid;
        }
        sb[t] = lo;
    }
    __syncthreads();
    float cnt = fmaxf((float)(sb[1] - sb[0]), 1.0f);
    z[t]      = selu_f(gsum[g * G + t] / cnt);
    z[t + 64] = selu_f(gsum[g * G + 64 + t] / cnt);
    __syncthreads();
    float a = ldf(lb1, t, f32);
    for (int k = 0; k < G; k++) a += z[k] * ldf(lw1, k * NHID + t, f32);
    z1[t] = selu_f(a);
    __syncthreads();
    if (t < 2) {
        float s = ldf(lb2, t, f32);
        for (int j = 0; j < NHID; j++) s += z1[j] * ldf(lw2, j * 2 + t, f32);
        z2[t] = s;
    }
    __syncthreads();
    if (t == 0) {
        float mx = fmaxf(z2[0], z2[1]);
        float l = mx + logf(expf(z2[0] - mx) + expf(z2[1] - mx));
        out[g * 2 + 0] = z2[0] - l;
        out[g * 2 + 1] = z2[1] - l;
    }
}

extern "C" void kernel_launch(void* const* d_in, const int* in_sizes, int n_in,
                              void* d_out, int out_size, void* d_ws, size_t ws_size,
                              hipStream_t stream) {
    const void* x    = d_in[0];
    const void* ei   = d_in[1];
    const void* batch= d_in[2];
    const void* W1   = d_in[3];
    const void* as1  = d_in[4];
    const void* ad1  = d_in[5];
    const void* b1   = d_in[6];
    const void* W2   = d_in[7];
    const void* as2  = d_in[8];
    const void* ad2  = d_in[9];
    const void* b2   = d_in[10];
    const void* lw1  = d_in[11];
    const void* lb1  = d_in[12];
    const void* lw2  = d_in[13];
    const void* lb2  = d_in[14];
    float* out = (float*)d_out;

    char* w = (char*)d_ws;
    size_t off = 0;
    auto alloc = [&](size_t bytes) -> char* {
        char* p = w + off;
        off = (off + bytes + 255) & ~(size_t)255;
        return p;
    };
    int*      flags  = (int*)alloc(256);
    unsigned* h2     = (unsigned*)alloc((size_t)N_NODES * 64 * 4);  // packed bf16x2
    ushort*   abuf   = (ushort*)alloc((size_t)N_NODES * G * 2);     // bf16 L1 output
    float2*   es2    = (float2*)alloc((size_t)N_NODES * 8);
    int2*     rowse  = (int2*)alloc((size_t)N_NODES * 8);
    unsigned* pairs  = (unsigned*)alloc((size_t)NBUCK * NBA * CELL * 4);  // 9.8 MB
    int*      cnts   = (int*)alloc((size_t)NBUCK * NBA * 4);
    ushort*   srcs   = (ushort*)alloc((size_t)NBUCK * CAPB * 2);
    float*    gsum   = (float*)alloc((size_t)NGRAPH * G * 4);
    ushort*   wt1    = (ushort*)alloc((size_t)IN_F * G * 2 * 2);   // hi+lo frag-ordered
    ushort*   wt2    = (ushort*)alloc((size_t)G * G * 2 * 2);

    unsigned gemm_grid = (N_NODES + 63) / 64;   // 782
    unsigned agg_grid = (N_NODES + 3) / 4;      // 12500

    // 1. edge bucketing (+ inline dtype detect, flags publish, fused wt)
    binA_kernel<<<NBA, 256, 0, stream>>>(ei, pairs, cnts, flags, x, W1, W2, wt1, wt2);
    // 2. hybrid: binB (CSR finalize + self-loops) + layer-1 GEMM
    binB_gemm_kernel<IN_F><<<NBUCK + gemm_grid, 256, 0, stream>>>(
        pairs, cnts, rowse, srcs, x, wt1, h2, flags, as1, ad1, es2);
    // 3. layer-1 aggregate -> abuf
    gat_agg_kernel<0><<<agg_grid, 256, 0, stream>>>(h2, rowse, srcs, es2, b1, abuf,
                                                    nullptr, nullptr, flags);
    // 4. layer-2 GEMM (+ gsum zero by block 0)
    gemm_mfma_kernel<G><<<gemm_grid, 256, 0, stream>>>(abuf, wt2, h2, 2, flags,
                                                       as2, ad2, es2, gsum);
    // 5. layer-2 aggregate + fused global_mean_pool (atomic gsum)
    gat_agg_kernel<1><<<agg_grid, 256, 0, stream>>>(h2, rowse, srcs, es2, b2, nullptr,
                                                    batch, gsum, flags);
    // 6. head (counts via binary search on sorted batch)
    head_kernel<<<NGRAPH, 64, 0, stream>>>(gsum, batch, lw1, lb1, lw2, lb2, out, flags);
}

// Round 7
// 338.139 us; speedup vs baseline: 1.9060x; 1.0388x over previous
//
#include <hip/hip_runtime.h>
#include <hip/hip_bf16.h>
#include <math.h>

#define N_NODES 50000
#define N_EDGES 800000
#define IN_F 256
#define G 128                    // 2*HID
#define NHID 64
#define NGRAPH 32
#define NBUCK ((N_NODES + 255) / 256)    // 196 buckets (dst>>8)
#define CAPB 8192                         // srcs capacity per bucket (mean 4352+256)
#define CELL 64                           // pairs capacity per (bucket, binA-block)
#define EPB 4096                          // edges per binA block
#define NBA ((N_EDGES + EPB - 1) / EPB)   // 196 (real edges only; self-loops direct)
#define RQ 8                              // src-range sort buckets (L2 slices)
#define RQSH 13                           // src>>13 -> 0..6 (slice = 1.6 MB of h2)

typedef __hip_bfloat16 bf16;
typedef unsigned short ushort;
typedef __attribute__((ext_vector_type(8))) short short8;
typedef __attribute__((ext_vector_type(4))) float f32x4;

// ---------- dtype-agnostic loads ----------
__device__ __forceinline__ float bf2f(ushort u) {
    union { unsigned u; float f; } c; c.u = ((unsigned)u) << 16; return c.f;
}
// round-to-nearest-even f32 -> bf16 (finite inputs)
__device__ __forceinline__ ushort f2bf(float f) {
    unsigned u = __float_as_uint(f);
    u += 0x7FFFu + ((u >> 16) & 1u);
    return (ushort)(u >> 16);
}
__device__ __forceinline__ float ldf(const void* p, long i, int f32) {
    return f32 ? ((const float*)p)[i] : bf2f(((const ushort*)p)[i]);
}
__device__ __forceinline__ int ldi(const void* p, long i, int i64) {
    return i64 ? (int)((const long long*)p)[i] : ((const int*)p)[i];
}

__device__ __forceinline__ float selu_f(float x) {
    const float sc = 1.0507009873554805f, al = 1.6732632423543772f;
    return x > 0.f ? sc * x : sc * al * expm1f(x);
}

// async global->LDS, 16 B/lane; lds base must be wave-uniform.
typedef const __attribute__((address_space(1))) void gas_void;
typedef __attribute__((address_space(3))) void las_void;
__device__ __forceinline__ void stage16(const void* g, void* l) {
    __builtin_amdgcn_global_load_lds((gas_void*)g, (las_void*)l, 16, 0, 0);
}

__device__ __forceinline__ void edge_sd(const void* __restrict__ ei, int e, int i64,
                                        int& s, int& d) {
    s = ldi(ei, e, i64);
    d = ldi(ei, (long)N_EDGES + e, i64);
    s = min(max(s, 0), N_NODES - 1);
    d = min(max(d, 0), N_NODES - 1);
}

// ---------------- CSR build v6: cells + self-loops + SRC-RANGE SORT -------------
// binA block k writes bucket-b records to cell (b,k), CELL=64 capacity (Poisson(21)
// -> P(>64)~1e-14). binB sorts each node's list by src>>13 (8 ranges): all resident
// agg waves then walk ranges in the same order, so concurrent gathers concentrate
// on a 1.6MB h2 slice that fits every XCD's 4MB L2 (round-6 model: gather is
// MSHR-capped at ~24 lines/CU x miss-latency; shorter latency => more BW).

__global__ __launch_bounds__(256) void binA_kernel(
    const void* __restrict__ ei, unsigned* __restrict__ pairs,
    int* __restrict__ cnts, int* __restrict__ flags,
    const void* __restrict__ x,
    const void* __restrict__ W1, const void* __restrict__ W2,
    ushort* __restrict__ wt1, ushort* __restrict__ wt2) {
    __shared__ int cnt[256], lofs[256], pcur[256];
    __shared__ unsigned stage[EPB];
    __shared__ int s_i64, s_f32;
    int t = threadIdx.x;

    // ---- inline dtype detect: wave0 -> i64 flag, wave1 -> f32 flag ----
    if (t < 64) {
        const unsigned* wu = (const unsigned*)ei;
        long j = 1 + (long)t * 24986;           // odd dwords, < 1.6M (int32-safe)
        unsigned long long bal = __ballot(wu[j] != 0u);
        if (t == 0) s_i64 = (__popcll(bal) < 16) ? 1 : 0;   // i64: high words all 0
    } else if (t < 128) {
        const unsigned* xu = (const unsigned*)x;
        unsigned u = xu[(long)(t - 64) * 100000];           // < 6.4M dwords (bf16-safe)
        unsigned e = (u >> 23) & 0xFF;
        unsigned long long bal = __ballot(u == 0u || (e >= 100 && e <= 140));
        if (t == 64) s_f32 = (__popcll(bal) >= 32) ? 1 : 0;
    }
    cnt[t] = 0;
    __syncthreads();
    int i64 = s_i64, f32 = s_f32;
    if (blockIdx.x == 0 && t == 0) { flags[0] = f32; flags[1] = i64; }

    int e0 = blockIdx.x * EPB;
    int nE = min(EPB, N_EDGES - e0);
    int sj[EPB / 256], dj[EPB / 256];
#pragma unroll
    for (int j = 0; j < EPB / 256; j++) {
        int idx = j * 256 + t;
        if (idx < nE) {
            edge_sd(ei, e0 + idx, i64, sj[j], dj[j]);
            atomicAdd(&cnt[dj[j] >> 8], 1);
        } else dj[j] = -1;
    }
    __syncthreads();
    lofs[t] = cnt[t];
    for (int off = 1; off < 256; off <<= 1) {
        __syncthreads();
        int v = (t >= off) ? lofs[t - off] : 0;
        __syncthreads();
        lofs[t] += v;
    }
    __syncthreads();
    int excl = lofs[t] - cnt[t];
    __syncthreads();
    lofs[t] = excl;
    pcur[t] = excl;
    __syncthreads();
#pragma unroll
    for (int j = 0; j < EPB / 256; j++) {
        if (dj[j] >= 0) {
            int b = dj[j] >> 8;
            int lp = atomicAdd(&pcur[b], 1);
            stage[lp] = (unsigned)sj[j] | ((unsigned)(dj[j] & 255) << 16) |
                        ((unsigned)b << 24);
        }
    }
    __syncthreads();
    for (int i = t; i < nE; i += 256) {      // per-bucket contiguous cell writes
        unsigned p = stage[i];
        int b = p >> 24;
        int off2 = i - lofs[b];
        if (off2 < CELL)
            pairs[((size_t)b * NBA + blockIdx.x) * CELL + off2] = p;
    }
    if (t < NBUCK) cnts[(size_t)t * NBA + blockIdx.x] = min(cnt[t], CELL);

    // ---- fused wt: split-bf16 (hi+lo) frag-reorder of W1,W2 (NBA*256 >= 49152) --
    int wi = blockIdx.x * 256 + t;
    if (wi < IN_F * G + G * G) {
        const void* W; ushort* wtp; int idx;
        if (wi < IN_F * G) { W = W1; wtp = wt1; idx = wi; }
        else { W = W2; wtp = wt2; idx = wi - IN_F * G; }
        int k = idx >> 7, n = idx & (G - 1);
        float wv = ldf(W, idx, f32);
        ushort h = f2bf(wv);
        ushort lo = f2bf(wv - bf2f(h));
        int c = k >> 5, q = (k >> 3) & 3, j = k & 7;
        int nt = n >> 4, n16 = n & 15;
        int lane = q * 16 + n16;
        size_t base = ((size_t)c * 16 + nt * 2) * 512 + lane * 8 + j;
        wtp[base] = h;           // hilo = 0
        wtp[base + 512] = lo;    // hilo = 1
    }
}

// binB v2: per-(node, src-range) counts -> scan -> rowse; self-loop inserted in
// its own range; scatter cells into range-sorted order.
__device__ __forceinline__ void binB_body(
    const unsigned* __restrict__ pairs, const int* __restrict__ cnts,
    int2* __restrict__ rowse, ushort* __restrict__ srcs,
    int b, int t, int* cntq /*256*RQ*/, int* sscan /*256*/, int* ccnt /*NBA*/) {
    if (t < NBA) ccnt[t] = cnts[(size_t)b * NBA + t];
#pragma unroll
    for (int j = 0; j < RQ; j++) cntq[t * RQ + j] = 0;
    int node = b * 256 + t;
    int valid = (node < N_NODES) ? 1 : 0;
    __syncthreads();
    if (valid) atomicAdd(&cntq[t * RQ + (node >> RQSH)], 1);   // self-loop count
    if (t < NBA) {                          // thread t streams cell (b,t)
        const unsigned* cp = pairs + ((size_t)b * NBA + t) * CELL;
        int n = ccnt[t];
        for (int i = 0; i < n; i++) {
            unsigned r = cp[i];
            int d = (r >> 16) & 255, q = (int)(r & 0xFFFFu) >> RQSH;
            atomicAdd(&cntq[d * RQ + q], 1);
        }
    }
    __syncthreads();
    // thread t owns node t's RQ counters: local scan + block scan of sums
    int c[RQ], lex[RQ], st = 0;
#pragma unroll
    for (int j = 0; j < RQ; j++) { c[j] = cntq[t * RQ + j]; lex[j] = st; st += c[j]; }
    sscan[t] = st;
    for (int off = 1; off < 256; off <<= 1) {
        __syncthreads();
        int v = (t >= off) ? sscan[t - off] : 0;
        __syncthreads();
        sscan[t] += v;
    }
    __syncthreads();
    int excl = sscan[t] - st;               // exclusive block prefix
    int base = b * CAPB;
    if (valid) rowse[node] = make_int2(base + excl, base + excl + st);
#pragma unroll
    for (int j = 0; j < RQ; j++) cntq[t * RQ + j] = base + excl + lex[j];  // cursors
    __syncthreads();
    if (valid) {                            // self-loop into its src-range slot
        int pos = atomicAdd(&cntq[t * RQ + (node >> RQSH)], 1);
        srcs[pos] = (ushort)node;
    }
    if (t < NBA) {
        const unsigned* cp = pairs + ((size_t)b * NBA + t) * CELL;
        int n = ccnt[t];
        for (int i = 0; i < n; i++) {
            unsigned r = cp[i];
            int d = (r >> 16) & 255, q = (int)(r & 0xFFFFu) >> RQSH;
            int pos = atomicAdd(&cntq[d * RQ + q], 1);
            srcs[pos] = (ushort)(r & 0xFFFFu);
        }
    }
}

// ---------------- GEMM body: MFMA split-bf16 (hi+lo), frag-ordered W -------------
// Block 256 thr = 4 waves; wave = 16 rows x 128 cols.
// H2: packed bf16x2, word l = {f_l, f_{l+64}}; es2[n] = {es, ed} (float2).
template <int K, bool AF32>
__device__ __forceinline__ void gemm_body(
    int bid, const void* __restrict__ A, const ushort* __restrict__ wt,
    unsigned* __restrict__ H2, const int* __restrict__ flags,
    const void* __restrict__ aS, const void* __restrict__ aD,
    float2* __restrict__ es2, short8* sB8) {
    constexpr int NC = K / 32;
    int wave = threadIdx.x >> 6, lane = threadIdx.x & 63;
    int quad = lane >> 4, n16 = lane & 15;
    int rb = bid * 64 + wave * 16;
    int rowa = min(rb + n16, N_NODES - 1);
    f32x4 acc[8];
#pragma unroll
    for (int t = 0; t < 8; t++) acc[t] = (f32x4){0.f, 0.f, 0.f, 0.f};

    for (int c = 0; c < NC; c++) {
#pragma unroll
        for (int i = 0; i < 4; i++) {
            int fw = wave * 4 + i;
            stage16(wt + ((size_t)c * 16 + fw) * 512 + lane * 8, &sB8[fw * 64]);
        }
        float av[8];
        if (AF32) {
            const float* ap = (const float*)A + (size_t)rowa * K + c * 32 + quad * 8;
            f32x4 a0 = *(const f32x4*)ap;
            f32x4 a1 = *(const f32x4*)(ap + 4);
#pragma unroll
            for (int j = 0; j < 4; j++) { av[j] = a0[j]; av[j + 4] = a1[j]; }
        } else {
            const ushort* ap = (const ushort*)A + (size_t)rowa * K + c * 32 + quad * 8;
#pragma unroll
            for (int j = 0; j < 8; j++) av[j] = bf2f(ap[j]);
        }
        short8 ahi, alo;
#pragma unroll
        for (int j = 0; j < 8; j++) {
            ushort h = f2bf(av[j]);
            ahi[j] = (short)h;
            alo[j] = (short)f2bf(av[j] - bf2f(h));
        }
        __syncthreads();   // staging complete
#pragma unroll
        for (int nt = 0; nt < 8; nt++) {
            short8 bh = sB8[(nt * 2 + 0) * 64 + lane];
            short8 bl = sB8[(nt * 2 + 1) * 64 + lane];
            acc[nt] = __builtin_amdgcn_mfma_f32_16x16x32_bf16(ahi, bh, acc[nt], 0, 0, 0);
            acc[nt] = __builtin_amdgcn_mfma_f32_16x16x32_bf16(ahi, bl, acc[nt], 0, 0, 0);
            acc[nt] = __builtin_amdgcn_mfma_f32_16x16x32_bf16(alo, bh, acc[nt], 0, 0, 0);
        }
        __syncthreads();
    }

    // epilogue: packed-bf16 H2 store + fused ead (es2 = {h.as, h.ad})
    int f32 = flags[0];
    float asv[8], adv[8];
#pragma unroll
    for (int nt = 0; nt < 8; nt++) {
        asv[nt] = ldf(aS, nt * 16 + n16, f32);
        adv[nt] = ldf(aD, nt * 16 + n16, f32);
    }
#pragma unroll
    for (int r = 0; r < 4; r++) {
        int ro = rb + quad * 4 + r;
        float s = 0.f, dv = 0.f;
#pragma unroll
        for (int nt = 0; nt < 8; nt++) {
            s += acc[nt][r] * asv[nt];
            dv += acc[nt][r] * adv[nt];
        }
        if (ro < N_NODES) {
#pragma unroll
            for (int nt = 0; nt < 4; nt++) {   // word c = {f_c, f_{c+64}}
                unsigned pack = (unsigned)f2bf(acc[nt][r]) |
                                ((unsigned)f2bf(acc[nt + 4][r]) << 16);
                H2[(size_t)ro * 64 + nt * 16 + n16] = pack;
            }
        }
#pragma unroll
        for (int off = 8; off; off >>= 1) {
            s += __shfl_xor(s, off);
            dv += __shfl_xor(dv, off);
        }
        if (n16 == 0 && ro < N_NODES) es2[ro] = make_float2(s, dv);
    }
}

// hybrid dispatch: blocks [0,NBUCK) run binB; blocks [NBUCK, NBUCK+gemm_grid)
// run layer-1 GEMM (independent work, same stream slot).
template <int K>
__global__ __launch_bounds__(256, 3) void binB_gemm_kernel(
    const unsigned* __restrict__ pairs, const int* __restrict__ cnts,
    int2* __restrict__ rowse, ushort* __restrict__ srcs,
    const void* __restrict__ A, const ushort* __restrict__ wt,
    unsigned* __restrict__ H2, const int* __restrict__ flags,
    const void* __restrict__ aS, const void* __restrict__ aD,
    float2* __restrict__ es2) {
    __shared__ short8 sB8[16 * 64];   // 16 KB (gemm blocks)
    __shared__ int s_cntq[256 * RQ];  // 8 KB (binB blocks)
    __shared__ int s_scan[256], s_ccnt[NBA];
    if (blockIdx.x < NBUCK) {
        binB_body(pairs, cnts, rowse, srcs, blockIdx.x, threadIdx.x,
                  s_cntq, s_scan, s_ccnt);
        return;
    }
    int bid = blockIdx.x - NBUCK;
    if (flags[0]) gemm_body<K, true>(bid, A, wt, H2, flags, aS, aD, es2, sB8);
    else          gemm_body<K, false>(bid, A, wt, H2, flags, aS, aD, es2, sB8);
}

// standalone layer-2 GEMM (a_mode 2: internal bf16 A); block 0 zeroes gsum for
// the following fused agg+pool dispatch.
template <int K>
__global__ __launch_bounds__(256, 3) void gemm_mfma_kernel(
    const void* __restrict__ A, const ushort* __restrict__ wt,
    unsigned* __restrict__ H2, int a_mode, const int* __restrict__ flags,
    const void* __restrict__ aS, const void* __restrict__ aD,
    float2* __restrict__ es2, float* __restrict__ zbuf) {
    __shared__ short8 sB8[16 * 64];
    if (zbuf != nullptr && blockIdx.x == 0) {
        for (int i = threadIdx.x; i < NGRAPH * G; i += 256) zbuf[i] = 0.f;
    }
    int af32 = (a_mode == 2) ? 0 : flags[0];   // block-uniform
    if (af32) gemm_body<K, true>(blockIdx.x, A, wt, H2, flags, aS, aD, es2, sB8);
    else      gemm_body<K, false>(blockIdx.x, A, wt, H2, flags, aS, aD, es2, sB8);
}

// Fused GAT aggregate: exact r4 structure (best measured: 149-155us, VGPR 28).
// 1 node/wave, readlane broadcast (SGPR edge state), 8-deep scalar gather.
// Round-6 lesson: depth 16 = neutral (gather is throughput-capped, not
// per-wave-latency-capped); srcs now src-range-sorted for L2 slice locality.
template <int POOL>
__global__ __launch_bounds__(256) void gat_agg_kernel(
    const unsigned* __restrict__ h2, const int2* __restrict__ rowse,
    const ushort* __restrict__ srcs, const float2* __restrict__ es2,
    const void* __restrict__ bias, ushort* __restrict__ outb,
    const void* __restrict__ batch, float* __restrict__ gsum,
    const int* __restrict__ flags) {
    int node = blockIdx.x * 4 + (threadIdx.x >> 6);
    if (node >= N_NODES) return;            // wave-uniform
    int l = threadIdx.x & 63;
    int2 se = rowse[node];
    int start = se.x, end = se.y;
    float edd = es2[node].y;
    float m = -INFINITY, den = 0.f;
    float acc0 = 0.f, acc1 = 0.f;
    for (int c0 = start; c0 < end; c0 += 64) {
        int cn = min(end - c0, 64);
        int s = 0; float v = -INFINITY;
        if (l < cn) {
            s = (int)srcs[c0 + l];
            v = es2[s].x + edd;
            v = v >= 0.f ? v : 0.2f * v;    // LeakyReLU(0.2)
        }
        float mc = v;
#pragma unroll
        for (int off = 32; off; off >>= 1) mc = fmaxf(mc, __shfl_xor(mc, off));
        float mnew = fmaxf(m, mc);
        float scale = expf(m - mnew);        // m=-INF first chunk -> 0
        float p = (l < cn) ? expf(v - mnew) : 0.f;
        float lsum = p;
#pragma unroll
        for (int off = 32; off; off >>= 1) lsum += __shfl_xor(lsum, off);
        den = den * scale + lsum;
        acc0 *= scale; acc1 *= scale;
        int cnr = (cn + 7) & ~7;             // round up: tail lanes have p=0
        for (int i = 0; i < cnr; i += 8) {
            int sis[8]; float pis[8]; unsigned hv[8];
#pragma unroll
            for (int j = 0; j < 8; j++) {
                sis[j] = __builtin_amdgcn_readlane(s, i + j);
                pis[j] = __uint_as_float(
                    __builtin_amdgcn_readlane(__float_as_uint(p), i + j));
            }
#pragma unroll
            for (int j = 0; j < 8; j++)      // 8 outstanding 256B wave-loads
                hv[j] = h2[(size_t)sis[j] * 64 + l];
#pragma unroll
            for (int j = 0; j < 8; j++) {
                acc0 += pis[j] * bf2f((ushort)(hv[j] & 0xFFFFu));
                acc1 += pis[j] * bf2f((ushort)(hv[j] >> 16));
            }
        }
        m = mnew;
    }
    float inv = 1.f / (den + 1e-16f);
    int f32 = flags[0];
    float o0 = selu_f(acc0 * inv + ldf(bias, l, f32));
    float o1 = selu_f(acc1 * inv + ldf(bias, l + 64, f32));
    if (POOL) {
        int gid = min(max(ldi(batch, node, flags[1]), 0), NGRAPH - 1);
        atomicAdd(&gsum[gid * G + l], o0);
        atomicAdd(&gsum[gid * G + 64 + l], o1);
    } else {
        outb[(size_t)node * G + l]      = f2bf(o0);
        outb[(size_t)node * G + l + 64] = f2bf(o1);
    }
}

// pooled -> selu -> lin1+selu -> lin2 -> log_softmax; counts via binary search
// over the sorted batch vector. OUTPUT FLOAT32.
__global__ void head_kernel(const float* __restrict__ gsum, const void* __restrict__ batch,
                            const void* __restrict__ lw1, const void* __restrict__ lb1,
                            const void* __restrict__ lw2, const void* __restrict__ lb2,
                            float* __restrict__ out, const int* __restrict__ flags) {
    int g = blockIdx.x, t = threadIdx.x;  // 64
    int f32 = flags[0], i64 = flags[1];
    __shared__ float z[G];
    __shared__ float z1[NHID];
    __shared__ float z2[2];
    __shared__ int sb[2];
    if (t < 2) {                       // lower_bound(g), lower_bound(g+1)
        int target = g + t;
        int lo = 0, hi = N_NODES;
        while (lo < hi) {
            int mid = (lo + hi) >> 1;
            int v = ldi(batch, mid, i64);
            if (v < target) lo = mid + 1; else hi = mid;
        }
        sb[t] = lo;
    }
    __syncthreads();
    float cnt = fmaxf((float)(sb[1] - sb[0]), 1.0f);
    z[t]      = selu_f(gsum[g * G + t] / cnt);
    z[t + 64] = selu_f(gsum[g * G + 64 + t] / cnt);
    __syncthreads();
    float a = ldf(lb1, t, f32);
    for (int k = 0; k < G; k++) a += z[k] * ldf(lw1, k * NHID + t, f32);
    z1[t] = selu_f(a);
    __syncthreads();
    if (t < 2) {
        float s = ldf(lb2, t, f32);
        for (int j = 0; j < NHID; j++) s += z1[j] * ldf(lw2, j * 2 + t, f32);
        z2[t] = s;
    }
    __syncthreads();
    if (t == 0) {
        float mx = fmaxf(z2[0], z2[1]);
        float l = mx + logf(expf(z2[0] - mx) + expf(z2[1] - mx));
        out[g * 2 + 0] = z2[0] - l;
        out[g * 2 + 1] = z2[1] - l;
    }
}

extern "C" void kernel_launch(void* const* d_in, const int* in_sizes, int n_in,
                              void* d_out, int out_size, void* d_ws, size_t ws_size,
                              hipStream_t stream) {
    const void* x    = d_in[0];
    const void* ei   = d_in[1];
    const void* batch= d_in[2];
    const void* W1   = d_in[3];
    const void* as1  = d_in[4];
    const void* ad1  = d_in[5];
    const void* b1   = d_in[6];
    const void* W2   = d_in[7];
    const void* as2  = d_in[8];
    const void* ad2  = d_in[9];
    const void* b2   = d_in[10];
    const void* lw1  = d_in[11];
    const void* lb1  = d_in[12];
    const void* lw2  = d_in[13];
    const void* lb2  = d_in[14];
    float* out = (float*)d_out;

    char* w = (char*)d_ws;
    size_t off = 0;
    auto alloc = [&](size_t bytes) -> char* {
        char* p = w + off;
        off = (off + bytes + 255) & ~(size_t)255;
        return p;
    };
    int*      flags  = (int*)alloc(256);
    unsigned* h2     = (unsigned*)alloc((size_t)N_NODES * 64 * 4);  // packed bf16x2
    ushort*   abuf   = (ushort*)alloc((size_t)N_NODES * G * 2);     // bf16 L1 output
    float2*   es2    = (float2*)alloc((size_t)N_NODES * 8);
    int2*     rowse  = (int2*)alloc((size_t)N_NODES * 8);
    unsigned* pairs  = (unsigned*)alloc((size_t)NBUCK * NBA * CELL * 4);  // 9.8 MB
    int*      cnts   = (int*)alloc((size_t)NBUCK * NBA * 4);
    ushort*   srcs   = (ushort*)alloc((size_t)NBUCK * CAPB * 2);
    float*    gsum   = (float*)alloc((size_t)NGRAPH * G * 4);
    ushort*   wt1    = (ushort*)alloc((size_t)IN_F * G * 2 * 2);   // hi+lo frag-ordered
    ushort*   wt2    = (ushort*)alloc((size_t)G * G * 2 * 2);

    unsigned gemm_grid = (N_NODES + 63) / 64;   // 782
    unsigned agg_grid = (N_NODES + 3) / 4;      // 12500

    // 1. edge bucketing (+ inline dtype detect, flags publish, fused wt)
    binA_kernel<<<NBA, 256, 0, stream>>>(ei, pairs, cnts, flags, x, W1, W2, wt1, wt2);
    // 2. hybrid: binB (CSR finalize + self-loops + src-range sort) + layer-1 GEMM
    binB_gemm_kernel<IN_F><<<NBUCK + gemm_grid, 256, 0, stream>>>(
        pairs, cnts, rowse, srcs, x, wt1, h2, flags, as1, ad1, es2);
    // 3. layer-1 aggregate -> abuf
    gat_agg_kernel<0><<<agg_grid, 256, 0, stream>>>(h2, rowse, srcs, es2, b1, abuf,
                                                    nullptr, nullptr, flags);
    // 4. layer-2 GEMM (+ gsum zero by block 0)
    gemm_mfma_kernel<G><<<gemm_grid, 256, 0, stream>>>(abuf, wt2, h2, 2, flags,
                                                       as2, ad2, es2, gsum);
    // 5. layer-2 aggregate + fused global_mean_pool (atomic gsum)
    gat_agg_kernel<1><<<agg_grid, 256, 0, stream>>>(h2, rowse, srcs, es2, b2, nullptr,
                                                    batch, gsum, flags);
    // 6. head (counts via binary search on sorted batch)
    head_kernel<<<NGRAPH, 64, 0, stream>>>(gsum, batch, lw1, lb1, lw2, lb2, out, flags);
}